// Round 4
// baseline (727.436 us; speedup 1.0000x reference)
//
#include <hip/hip_runtime.h>
#include <math.h>

#define N_NODES 100000
#define SCAN_CHUNK 2048
#define DEG_BLOCKS 1024

struct alignas(16) f4 { float v[4]; };
struct alignas(8) us4 { unsigned short v[4]; };

__device__ inline unsigned short f2bf(float x) {
    union { float f; unsigned int u; } v;
    v.f = x;
    unsigned int r = v.u + 0x7FFF + ((v.u >> 16) & 1);
    return (unsigned short)(r >> 16);
}

__device__ inline float bf2f(unsigned short h) {
    union { unsigned int u; float f; } v;
    v.u = ((unsigned int)h) << 16;
    return v.f;
}

// ---------------- K1: fused degrees (blocks [0,DEG_BLOCKS)) + layer-0 GEMM ----------------
// GEMM is UNSCALED (ns folded into layer-0 aggregation later): Hb0 = bf16(feats @ W0)
__global__ __launch_bounds__(256) void k_deg_gemm0(const int* __restrict__ src,
                                                   const int* __restrict__ dst,
                                                   int E,
                                                   int* __restrict__ degs,
                                                   int* __restrict__ degd,
                                                   const float* __restrict__ A,
                                                   const float* __restrict__ W,
                                                   unsigned short* __restrict__ C,
                                                   int n) {
    constexpr int K = 128, AS = K + 4;
    __shared__ __align__(16) float Ws[K * 64];
    __shared__ __align__(16) float Asm[64 * AS];

    const int tid = threadIdx.x;

    if (blockIdx.x < DEG_BLOCKS) {
        // ---- degree path: edge-parallel grid-stride, fire atomics ----
        for (int i = blockIdx.x * 256 + tid; i < E; i += DEG_BLOCKS * 256) {
            atomicAdd(&degs[src[i]], 1);
            atomicAdd(&degd[dst[i]], 1);
        }
        return;
    }

    // ---- GEMM path: 64x64 tile, K=128, OUT=64 ----
    const int r0 = (blockIdx.x - DEG_BLOCKS) * 64;

    for (int i = tid; i < K * 64; i += 256) {
        int k = i >> 6;
        int c = i & 63;
        Ws[i] = W[k * 64 + c];
    }
    for (int i = tid * 4; i < 64 * K; i += 1024) {
        int r = i / K;
        int c = i - r * K;
        f4 v;
        if (r0 + r < n) {
            v = *(const f4*)&A[(size_t)(r0 + r) * K + c];
        } else {
            v.v[0] = v.v[1] = v.v[2] = v.v[3] = 0.0f;
        }
        *(f4*)&Asm[r * AS + c] = v;
    }
    __syncthreads();

    const int tr = tid >> 4;
    const int tc = tid & 15;

    float acc[4][4];
#pragma unroll
    for (int i = 0; i < 4; ++i)
#pragma unroll
        for (int j = 0; j < 4; ++j) acc[i][j] = 0.0f;

    for (int k = 0; k < K; k += 4) {
        f4 av[4], wv[4];
#pragma unroll
        for (int i = 0; i < 4; ++i)
            av[i] = *(const f4*)&Asm[(tr * 4 + i) * AS + k];
#pragma unroll
        for (int kk = 0; kk < 4; ++kk)
            wv[kk] = *(const f4*)&Ws[(k + kk) * 64 + tc * 4];
#pragma unroll
        for (int i = 0; i < 4; ++i)
#pragma unroll
            for (int j = 0; j < 4; ++j)
                acc[i][j] += av[i].v[0] * wv[0].v[j] + av[i].v[1] * wv[1].v[j] +
                             av[i].v[2] * wv[2].v[j] + av[i].v[3] * wv[3].v[j];
    }

#pragma unroll
    for (int i = 0; i < 4; ++i) {
        int row = r0 + tr * 4 + i;
        if (row < n) {
            us4 o;
#pragma unroll
            for (int j = 0; j < 4; ++j) o.v[j] = f2bf(acc[i][j]);
            *(us4*)&C[(size_t)row * 64 + tc * 4] = o;
        }
    }
}

// ---------------- scan of degd -> row_ptr (+ norms fused) ----------------
__global__ __launch_bounds__(256) void k_block_sums(const int* __restrict__ deg, int n,
                                                    int* __restrict__ bsums) {
    __shared__ int sdata[256];
    int base = blockIdx.x * SCAN_CHUNK;
    int s = 0;
    for (int i = threadIdx.x; i < SCAN_CHUNK; i += 256) {
        int idx = base + i;
        s += (idx < n) ? deg[idx] : 0;
    }
    sdata[threadIdx.x] = s;
    __syncthreads();
    for (int off = 128; off > 0; off >>= 1) {
        if (threadIdx.x < off) sdata[threadIdx.x] += sdata[threadIdx.x + off];
        __syncthreads();
    }
    if (threadIdx.x == 0) bsums[blockIdx.x] = sdata[0];
}

__global__ void k_scan_bsums(int* __restrict__ bsums, int nb, int* __restrict__ row_ptr, int n) {
    if (threadIdx.x == 0 && blockIdx.x == 0) {
        int acc = 0;
        for (int i = 0; i < nb; ++i) {
            int v = bsums[i];
            bsums[i] = acc;
            acc += v;
        }
        row_ptr[n] = acc;
    }
}

__global__ __launch_bounds__(256) void k_scan_write(const int* __restrict__ degd,
                                                    const int* __restrict__ degs,
                                                    int n,
                                                    const int* __restrict__ bsums,
                                                    int* __restrict__ row_ptr,
                                                    int* __restrict__ cursor,
                                                    float* __restrict__ ns,
                                                    float* __restrict__ nd) {
    __shared__ int sdata[256];
    int tid = threadIdx.x;
    int tbase = blockIdx.x * SCAN_CHUNK + tid * 8;
    int v[8];
    int s = 0;
#pragma unroll
    for (int j = 0; j < 8; ++j) {
        int idx = tbase + j;
        v[j] = (idx < n) ? degd[idx] : 0;
        s += v[j];
    }
    sdata[tid] = s;
    __syncthreads();
    for (int off = 1; off < 256; off <<= 1) {
        int t = (tid >= off) ? sdata[tid - off] : 0;
        __syncthreads();
        sdata[tid] += t;
        __syncthreads();
    }
    int excl = sdata[tid] - s + bsums[blockIdx.x];
#pragma unroll
    for (int j = 0; j < 8; ++j) {
        int idx = tbase + j;
        if (idx < n) {
            row_ptr[idx] = excl;
            cursor[idx] = excl;
            int a = degs[idx];
            ns[idx] = (a > 0) ? rsqrtf((float)a) : 0.0f;
            nd[idx] = (v[j] > 0) ? rsqrtf((float)v[j]) : 0.0f;
        }
        excl += v[j];
    }
}

// ---------------- scatter (single pass) ----------------
__global__ __launch_bounds__(256) void k_scatter(const int* __restrict__ src,
                                                 const int* __restrict__ dst,
                                                 int E,
                                                 int* __restrict__ cursor,
                                                 int* __restrict__ csr_src) {
    int i = blockIdx.x * 256 + threadIdx.x;
    if (i < E) {
        int d = dst[i];
        int pos = atomicAdd(&cursor[d], 1);
        csr_src[pos] = src[i];
    }
}

// ---------------- fused: agg(bf16 H, stride 64) + *nd+b + relu + log_softmax -> LDS tile
//                  -> GEMM tile @ W (64xOUT, zero-padded) * ns[row] -> bf16 Hout ----------------
// Block owns 64 nodes; 4 waves x 16 nodes each for the agg stage, then 64x64 GEMM.
template <int OUT, bool FOLD_NS>
__global__ __launch_bounds__(256) void k_agg_gemm(const int* __restrict__ row_ptr,
                                                  const int* __restrict__ csr_src,
                                                  const unsigned short* __restrict__ H,
                                                  const float* __restrict__ ns,
                                                  const float* __restrict__ nd,
                                                  const float* __restrict__ b,
                                                  const float* __restrict__ W,
                                                  unsigned short* __restrict__ Hout,
                                                  int n) {
    constexpr int AS = 68; // 64 + 4 pad; 68*4 bytes = 272, 16B-aligned rows
    __shared__ __align__(16) float Asm[64 * AS];
    __shared__ __align__(16) float Ws[64 * 64];

    const int tid = threadIdx.x;
    const int lane = tid & 63;
    const int wave = tid >> 6;
    const int r0 = blockIdx.x * 64;

    // stage W zero-padded to 64 cols
    for (int i = tid; i < 64 * 64; i += 256) {
        int k = i >> 6;
        int c = i & 63;
        Ws[i] = (c < OUT) ? W[k * OUT + c] : 0.0f;
    }

    const float bias = b[lane]; // stage-A width is always 64

    // ---- stage A: aggregate + epilogue + log_softmax, 16 nodes per wave ----
    for (int t = 0; t < 16; ++t) {
        int v = r0 + wave * 16 + t;
        float val = 0.0f;
        if (v < n) {
            int beg = row_ptr[v];
            int end = row_ptr[v + 1];
            float a0 = 0.f, a1 = 0.f, a2 = 0.f, a3 = 0.f;
            for (int i = beg; i < end; i += 64) {
                int cnt = min(64, end - i);
                int idx = (lane < cnt) ? csr_src[i + lane] : 0;
                float nsv = 0.0f;
                if (FOLD_NS) nsv = (lane < cnt) ? ns[idx] : 0.0f;
                int j = 0;
                for (; j + 4 <= cnt; j += 4) {
                    int s0 = __shfl(idx, j);
                    int s1 = __shfl(idx, j + 1);
                    int s2 = __shfl(idx, j + 2);
                    int s3 = __shfl(idx, j + 3);
                    if (FOLD_NS) {
                        float f0 = __shfl(nsv, j);
                        float f1 = __shfl(nsv, j + 1);
                        float f2 = __shfl(nsv, j + 2);
                        float f3 = __shfl(nsv, j + 3);
                        a0 += bf2f(H[(size_t)s0 * 64 + lane]) * f0;
                        a1 += bf2f(H[(size_t)s1 * 64 + lane]) * f1;
                        a2 += bf2f(H[(size_t)s2 * 64 + lane]) * f2;
                        a3 += bf2f(H[(size_t)s3 * 64 + lane]) * f3;
                    } else {
                        a0 += bf2f(H[(size_t)s0 * 64 + lane]);
                        a1 += bf2f(H[(size_t)s1 * 64 + lane]);
                        a2 += bf2f(H[(size_t)s2 * 64 + lane]);
                        a3 += bf2f(H[(size_t)s3 * 64 + lane]);
                    }
                }
                for (; j < cnt; ++j) {
                    int s = __shfl(idx, j);
                    if (FOLD_NS) {
                        float f = __shfl(nsv, j);
                        a0 += bf2f(H[(size_t)s * 64 + lane]) * f;
                    } else {
                        a0 += bf2f(H[(size_t)s * 64 + lane]);
                    }
                }
            }
            float x = (a0 + a1) + (a2 + a3);
            x = fmaxf(x * nd[v] + bias, 0.0f); // relu (both fused layers have it)
            float m = x;
#pragma unroll
            for (int off = 32; off > 0; off >>= 1) m = fmaxf(m, __shfl_xor(m, off));
            float ex = expf(x - m);
            float ssum = ex;
#pragma unroll
            for (int off = 32; off > 0; off >>= 1) ssum += __shfl_xor(ssum, off);
            val = (x - m) - logf(ssum);
        }
        Asm[(wave * 16 + t) * AS + lane] = val;
    }
    __syncthreads();

    // ---- stage B: 64x64 GEMM, scale by ns[row], bf16 out (stride OUT) ----
    const int tr = tid >> 4;
    const int tc = tid & 15;

    float acc[4][4];
#pragma unroll
    for (int i = 0; i < 4; ++i)
#pragma unroll
        for (int j = 0; j < 4; ++j) acc[i][j] = 0.0f;

    for (int k = 0; k < 64; k += 4) {
        f4 av[4], wv[4];
#pragma unroll
        for (int i = 0; i < 4; ++i)
            av[i] = *(const f4*)&Asm[(tr * 4 + i) * AS + k];
#pragma unroll
        for (int kk = 0; kk < 4; ++kk)
            wv[kk] = *(const f4*)&Ws[(k + kk) * 64 + tc * 4];
#pragma unroll
        for (int i = 0; i < 4; ++i)
#pragma unroll
            for (int j = 0; j < 4; ++j)
                acc[i][j] += av[i].v[0] * wv[0].v[j] + av[i].v[1] * wv[1].v[j] +
                             av[i].v[2] * wv[2].v[j] + av[i].v[3] * wv[3].v[j];
    }

    if (tc * 4 < OUT) {
#pragma unroll
        for (int i = 0; i < 4; ++i) {
            int row = r0 + tr * 4 + i;
            if (row < n) {
                float s = ns[row];
                us4 o;
#pragma unroll
                for (int j = 0; j < 4; ++j) o.v[j] = f2bf(acc[i][j] * s);
                *(us4*)&Hout[(size_t)row * OUT + tc * 4] = o;
            }
        }
    }
}

// ---------------- final: agg(bf16 H, stride 40) + *nd+b + log_softmax -> fp32 out ----------------
__global__ __launch_bounds__(256) void k_agg_final(const int* __restrict__ row_ptr,
                                                   const int* __restrict__ csr_src,
                                                   const unsigned short* __restrict__ H,
                                                   const float* __restrict__ nd,
                                                   const float* __restrict__ b,
                                                   float* __restrict__ Out,
                                                   int n) {
    constexpr int D = 40;
    int node = blockIdx.x * 4 + (threadIdx.x >> 6);
    int lane = threadIdx.x & 63;
    if (node >= n) return;

    int beg = row_ptr[node];
    int end = row_ptr[node + 1];
    bool active = lane < D;

    float a0 = 0.f, a1 = 0.f, a2 = 0.f, a3 = 0.f;
    for (int i = beg; i < end; i += 64) {
        int cnt = min(64, end - i);
        int idx = (lane < cnt) ? csr_src[i + lane] : 0;
        int j = 0;
        for (; j + 4 <= cnt; j += 4) {
            int s0 = __shfl(idx, j);
            int s1 = __shfl(idx, j + 1);
            int s2 = __shfl(idx, j + 2);
            int s3 = __shfl(idx, j + 3);
            if (active) {
                a0 += bf2f(H[(size_t)s0 * D + lane]);
                a1 += bf2f(H[(size_t)s1 * D + lane]);
                a2 += bf2f(H[(size_t)s2 * D + lane]);
                a3 += bf2f(H[(size_t)s3 * D + lane]);
            }
        }
        for (; j < cnt; ++j) {
            int s = __shfl(idx, j);
            if (active) a0 += bf2f(H[(size_t)s * D + lane]);
        }
    }
    float acc = (a0 + a1) + (a2 + a3);

    float x = -INFINITY;
    if (active) x = acc * nd[node] + b[lane];
    float m = x;
#pragma unroll
    for (int off = 32; off > 0; off >>= 1) m = fmaxf(m, __shfl_xor(m, off));
    float ex = active ? expf(x - m) : 0.0f;
    float ssum = ex;
#pragma unroll
    for (int off = 32; off > 0; off >>= 1) ssum += __shfl_xor(ssum, off);
    if (active) Out[(size_t)node * D + lane] = (x - m) - logf(ssum);
}

extern "C" void kernel_launch(void* const* d_in, const int* in_sizes, int n_in,
                              void* d_out, int out_size, void* d_ws, size_t ws_size,
                              hipStream_t stream) {
    const float* feats = (const float*)d_in[0];
    const int* src = (const int*)d_in[1];
    const int* dst = (const int*)d_in[2];
    const float* W0 = (const float*)d_in[3];
    const float* b0 = (const float*)d_in[4];
    const float* W1 = (const float*)d_in[5];
    const float* b1 = (const float*)d_in[6];
    const float* W2 = (const float*)d_in[7];
    const float* b2 = (const float*)d_in[8];
    float* out = (float*)d_out;

    const int N = N_NODES;
    const int E = in_sizes[1];
    const int NB = (N + SCAN_CHUNK - 1) / SCAN_CHUNK;
    const int GT = (N + 63) / 64; // gemm/agg tiles

    // workspace layout (~42 MB)
    float* ns = (float*)d_ws;                          // N
    float* nd = ns + N;                                // N
    unsigned short* Hb0 = (unsigned short*)(nd + N);   // N*64 bf16
    unsigned short* Hb1 = Hb0 + (size_t)N * 64;        // N*64 bf16
    unsigned short* Hb2 = Hb1 + (size_t)N * 64;        // N*40 bf16
    int* row_ptr = (int*)(Hb2 + (size_t)N * 40);       // N+1
    int* cursor = row_ptr + (N + 1);                   // N
    int* csr_src = cursor + N;                         // E
    int* degS = csr_src + E;                           // N
    int* degD = degS + N;                              // N
    int* bsums = degD + N;                             // NB

    // 1) zero degree counters, then fused degrees + layer-0 GEMM (unscaled)
    hipMemsetAsync(degS, 0, (size_t)N * sizeof(int), stream);
    hipMemsetAsync(degD, 0, (size_t)N * sizeof(int), stream);
    k_deg_gemm0<<<DEG_BLOCKS + GT, 256, 0, stream>>>(src, dst, E, degS, degD,
                                                     feats, W0, Hb0, N);

    // 2) scan degD -> row_ptr (+ norms), then single-pass scatter
    k_block_sums<<<NB, 256, 0, stream>>>(degD, N, bsums);
    k_scan_bsums<<<1, 64, 0, stream>>>(bsums, NB, row_ptr, N);
    k_scan_write<<<NB, 256, 0, stream>>>(degD, degS, N, bsums, row_ptr, cursor, ns, nd);
    k_scatter<<<(E + 255) / 256, 256, 0, stream>>>(src, dst, E, cursor, csr_src);

    // 3) layer 0 agg (folds ns[src]) + softmax + layer-1 GEMM -> Hb1
    k_agg_gemm<64, true><<<GT, 256, 0, stream>>>(row_ptr, csr_src, Hb0, ns, nd, b0, W1, Hb1, N);

    // 4) layer 1 agg + softmax + layer-2 GEMM (OUT=40) -> Hb2
    k_agg_gemm<40, false><<<GT, 256, 0, stream>>>(row_ptr, csr_src, Hb1, ns, nd, b1, W2, Hb2, N);

    // 5) layer 2 agg + log_softmax -> out
    k_agg_final<<<(N + 3) / 4, 256, 0, stream>>>(row_ptr, csr_src, Hb2, nd, b2, out, N);
}

// Round 5
// 587.825 us; speedup vs baseline: 1.2375x; 1.2375x over previous
//
#include <hip/hip_runtime.h>
#include <math.h>

#define N_NODES 100000
#define SCAN_CHUNK 2048

struct alignas(16) f4 { float v[4]; };
struct alignas(8) us4 { unsigned short v[4]; };

__device__ inline unsigned short f2bf(float x) {
    union { float f; unsigned int u; } v;
    v.f = x;
    unsigned int r = v.u + 0x7FFF + ((v.u >> 16) & 1);
    return (unsigned short)(r >> 16);
}

__device__ inline float bf2f(unsigned short h) {
    union { unsigned int u; float f; } v;
    v.u = ((unsigned int)h) << 16;
    return v.f;
}

// ---------------- K1: interleaved degrees + layer-0 GEMM (unscaled) ----------------
// Even blocks: 64x64 GEMM tile (K=128 split into two 64-halves; LDS 33.8 KB -> 4 blocks/CU).
// Odd blocks: short degree chunk (~1024 edges) -> retires fast, keeps both types co-resident
// so GEMM VALU work hides under the atomic-fabric drain.
__global__ __launch_bounds__(256, 4) void k_deg_gemm0(const int* __restrict__ src,
                                                      const int* __restrict__ dst,
                                                      int E, int echunk,
                                                      int* __restrict__ degs,
                                                      int* __restrict__ degd,
                                                      const float* __restrict__ A,
                                                      const float* __restrict__ W,
                                                      unsigned short* __restrict__ C,
                                                      int n) {
    __shared__ __align__(16) float Ws[64 * 64];
    __shared__ __align__(16) float Asm[64 * 68];

    const int tid = threadIdx.x;
    const int idx = blockIdx.x >> 1;

    if (blockIdx.x & 1) {
        // ---- degree chunk ----
        int beg = idx * echunk + tid;
        int end = min(E, idx * echunk + echunk);
        for (int i = beg; i < end; i += 256) {
            atomicAdd(&degs[src[i]], 1);
            atomicAdd(&degd[dst[i]], 1);
        }
        return;
    }

    // ---- GEMM tile: rows [r0, r0+64), K=128, OUT=64, unscaled ----
    const int r0 = idx * 64;
    const int tr = tid >> 4;
    const int tc = tid & 15;

    float acc[4][4];
#pragma unroll
    for (int i = 0; i < 4; ++i)
#pragma unroll
        for (int j = 0; j < 4; ++j) acc[i][j] = 0.0f;

    for (int kh = 0; kh < 2; ++kh) {
        for (int i = tid; i < 64 * 64; i += 256) {
            int k = i >> 6;
            int c = i & 63;
            Ws[i] = W[(kh * 64 + k) * 64 + c];
        }
        for (int i = tid * 4; i < 64 * 64; i += 1024) {
            int r = i >> 6;
            int c = i & 63;
            f4 v;
            if (r0 + r < n) {
                v = *(const f4*)&A[(size_t)(r0 + r) * 128 + kh * 64 + c];
            } else {
                v.v[0] = v.v[1] = v.v[2] = v.v[3] = 0.0f;
            }
            *(f4*)&Asm[r * 68 + c] = v;
        }
        __syncthreads();

        for (int k = 0; k < 64; k += 4) {
            f4 av[4], wv[4];
#pragma unroll
            for (int i = 0; i < 4; ++i)
                av[i] = *(const f4*)&Asm[(tr * 4 + i) * 68 + k];
#pragma unroll
            for (int kk = 0; kk < 4; ++kk)
                wv[kk] = *(const f4*)&Ws[(k + kk) * 64 + tc * 4];
#pragma unroll
            for (int i = 0; i < 4; ++i)
#pragma unroll
                for (int j = 0; j < 4; ++j)
                    acc[i][j] += av[i].v[0] * wv[0].v[j] + av[i].v[1] * wv[1].v[j] +
                                 av[i].v[2] * wv[2].v[j] + av[i].v[3] * wv[3].v[j];
        }
        __syncthreads();
    }

#pragma unroll
    for (int i = 0; i < 4; ++i) {
        int row = r0 + tr * 4 + i;
        if (row < n) {
            us4 o;
#pragma unroll
            for (int j = 0; j < 4; ++j) o.v[j] = f2bf(acc[i][j]);
            *(us4*)&C[(size_t)row * 64 + tc * 4] = o;
        }
    }
}

// ---------------- scan of degd -> row_ptr (+ norms fused) ----------------
__global__ __launch_bounds__(256) void k_block_sums(const int* __restrict__ deg, int n,
                                                    int* __restrict__ bsums) {
    __shared__ int sdata[256];
    int base = blockIdx.x * SCAN_CHUNK;
    int s = 0;
    for (int i = threadIdx.x; i < SCAN_CHUNK; i += 256) {
        int idx = base + i;
        s += (idx < n) ? deg[idx] : 0;
    }
    sdata[threadIdx.x] = s;
    __syncthreads();
    for (int off = 128; off > 0; off >>= 1) {
        if (threadIdx.x < off) sdata[threadIdx.x] += sdata[threadIdx.x + off];
        __syncthreads();
    }
    if (threadIdx.x == 0) bsums[blockIdx.x] = sdata[0];
}

__global__ void k_scan_bsums(int* __restrict__ bsums, int nb, int* __restrict__ row_ptr, int n) {
    if (threadIdx.x == 0 && blockIdx.x == 0) {
        int acc = 0;
        for (int i = 0; i < nb; ++i) {
            int v = bsums[i];
            bsums[i] = acc;
            acc += v;
        }
        row_ptr[n] = acc;
    }
}

__global__ __launch_bounds__(256) void k_scan_write(const int* __restrict__ degd,
                                                    const int* __restrict__ degs,
                                                    int n,
                                                    const int* __restrict__ bsums,
                                                    int* __restrict__ row_ptr,
                                                    int* __restrict__ cursor,
                                                    float* __restrict__ ns,
                                                    float* __restrict__ nd) {
    __shared__ int sdata[256];
    int tid = threadIdx.x;
    int tbase = blockIdx.x * SCAN_CHUNK + tid * 8;
    int v[8];
    int s = 0;
#pragma unroll
    for (int j = 0; j < 8; ++j) {
        int idx = tbase + j;
        v[j] = (idx < n) ? degd[idx] : 0;
        s += v[j];
    }
    sdata[tid] = s;
    __syncthreads();
    for (int off = 1; off < 256; off <<= 1) {
        int t = (tid >= off) ? sdata[tid - off] : 0;
        __syncthreads();
        sdata[tid] += t;
        __syncthreads();
    }
    int excl = sdata[tid] - s + bsums[blockIdx.x];
#pragma unroll
    for (int j = 0; j < 8; ++j) {
        int idx = tbase + j;
        if (idx < n) {
            row_ptr[idx] = excl;
            cursor[idx] = excl;
            int a = degs[idx];
            ns[idx] = (a > 0) ? rsqrtf((float)a) : 0.0f;
            nd[idx] = (v[j] > 0) ? rsqrtf((float)v[j]) : 0.0f;
        }
        excl += v[j];
    }
}

// ---------------- scatter (single pass) ----------------
__global__ __launch_bounds__(256) void k_scatter(const int* __restrict__ src,
                                                 const int* __restrict__ dst,
                                                 int E,
                                                 int* __restrict__ cursor,
                                                 int* __restrict__ csr_src) {
    int i = blockIdx.x * 256 + threadIdx.x;
    if (i < E) {
        int d = dst[i];
        int pos = atomicAdd(&cursor[d], 1);
        csr_src[pos] = src[i];
    }
}

// ---------------- scale Hb0 rows by ns (deferred layer-0 ns) ----------------
__global__ __launch_bounds__(256) void k_scale_h(unsigned int* __restrict__ Hd,
                                                 const float* __restrict__ ns,
                                                 int n) {
    int i = blockIdx.x * 256 + threadIdx.x; // dword index, 32 dwords/row
    if (i < n * 32) {
        int row = i >> 5;
        float s = ns[row];
        unsigned int u = Hd[i];
        float lo = bf2f((unsigned short)(u & 0xffffu)) * s;
        float hi = bf2f((unsigned short)(u >> 16)) * s;
        Hd[i] = (unsigned int)f2bf(lo) | ((unsigned int)f2bf(hi) << 16);
    }
}

// ---------------- GEMM (K=64): C = bf16((A @ W) * ns[row]) ----------------
template <int OUT>
__global__ __launch_bounds__(256, 4) void k_gemm_scale(const float* __restrict__ A,
                                                       const float* __restrict__ W,
                                                       const float* __restrict__ ns,
                                                       unsigned short* __restrict__ C,
                                                       int n) {
    __shared__ __align__(16) float Ws[64 * 64];
    __shared__ __align__(16) float Asm[64 * 68];

    const int tid = threadIdx.x;
    const int r0 = blockIdx.x * 64;

    for (int i = tid; i < 64 * 64; i += 256) {
        int k = i >> 6;
        int c = i & 63;
        Ws[i] = (c < OUT) ? W[k * OUT + c] : 0.0f;
    }
    for (int i = tid * 4; i < 64 * 64; i += 1024) {
        int r = i >> 6;
        int c = i & 63;
        f4 v;
        if (r0 + r < n) {
            v = *(const f4*)&A[(size_t)(r0 + r) * 64 + c];
        } else {
            v.v[0] = v.v[1] = v.v[2] = v.v[3] = 0.0f;
        }
        *(f4*)&Asm[r * 68 + c] = v;
    }
    __syncthreads();

    const int tr = tid >> 4;
    const int tc = tid & 15;

    float acc[4][4];
#pragma unroll
    for (int i = 0; i < 4; ++i)
#pragma unroll
        for (int j = 0; j < 4; ++j) acc[i][j] = 0.0f;

    for (int k = 0; k < 64; k += 4) {
        f4 av[4], wv[4];
#pragma unroll
        for (int i = 0; i < 4; ++i)
            av[i] = *(const f4*)&Asm[(tr * 4 + i) * 68 + k];
#pragma unroll
        for (int kk = 0; kk < 4; ++kk)
            wv[kk] = *(const f4*)&Ws[(k + kk) * 64 + tc * 4];
#pragma unroll
        for (int i = 0; i < 4; ++i)
#pragma unroll
            for (int j = 0; j < 4; ++j)
                acc[i][j] += av[i].v[0] * wv[0].v[j] + av[i].v[1] * wv[1].v[j] +
                             av[i].v[2] * wv[2].v[j] + av[i].v[3] * wv[3].v[j];
    }

    if (tc * 4 < OUT) {
#pragma unroll
        for (int i = 0; i < 4; ++i) {
            int row = r0 + tr * 4 + i;
            if (row < n) {
                float s = ns[row];
                us4 o;
#pragma unroll
                for (int j = 0; j < 4; ++j) o.v[j] = f2bf(acc[i][j] * s);
                *(us4*)&C[(size_t)row * OUT + tc * 4] = o;
            }
        }
    }
}

// ---------------- fused CSR aggregate (bf16 gather) + (*nd + b) + relu? + log_softmax ----------------
template <int D, bool RELU>
__global__ __launch_bounds__(256) void k_agg_post(const int* __restrict__ row_ptr,
                                                  const int* __restrict__ csr_src,
                                                  const unsigned short* __restrict__ H,
                                                  const float* __restrict__ nd,
                                                  const float* __restrict__ b,
                                                  float* __restrict__ Out,
                                                  int n) {
    int node = blockIdx.x * 4 + (threadIdx.x >> 6);
    int lane = threadIdx.x & 63;
    if (node >= n) return;

    int beg = row_ptr[node];
    int end = row_ptr[node + 1];
    bool active = lane < D;

    float a0 = 0.f, a1 = 0.f, a2 = 0.f, a3 = 0.f;
    for (int i = beg; i < end; i += 64) {
        int cnt = min(64, end - i);
        int idx = (lane < cnt) ? csr_src[i + lane] : 0;
        int j = 0;
        for (; j + 4 <= cnt; j += 4) {
            int s0 = __shfl(idx, j);
            int s1 = __shfl(idx, j + 1);
            int s2 = __shfl(idx, j + 2);
            int s3 = __shfl(idx, j + 3);
            if (active) {
                a0 += bf2f(H[(size_t)s0 * D + lane]);
                a1 += bf2f(H[(size_t)s1 * D + lane]);
                a2 += bf2f(H[(size_t)s2 * D + lane]);
                a3 += bf2f(H[(size_t)s3 * D + lane]);
            }
        }
        for (; j < cnt; ++j) {
            int s = __shfl(idx, j);
            if (active) a0 += bf2f(H[(size_t)s * D + lane]);
        }
    }
    float acc = (a0 + a1) + (a2 + a3);

    float x = -INFINITY;
    if (active) {
        x = acc * nd[node] + b[lane];
        if (RELU) x = fmaxf(x, 0.0f);
    }
    float m = x;
#pragma unroll
    for (int off = 32; off > 0; off >>= 1) m = fmaxf(m, __shfl_xor(m, off));
    float ex = active ? expf(x - m) : 0.0f;
    float ssum = ex;
#pragma unroll
    for (int off = 32; off > 0; off >>= 1) ssum += __shfl_xor(ssum, off);
    if (active) Out[(size_t)node * D + lane] = (x - m) - logf(ssum);
}

extern "C" void kernel_launch(void* const* d_in, const int* in_sizes, int n_in,
                              void* d_out, int out_size, void* d_ws, size_t ws_size,
                              hipStream_t stream) {
    const float* feats = (const float*)d_in[0];
    const int* src = (const int*)d_in[1];
    const int* dst = (const int*)d_in[2];
    const float* W0 = (const float*)d_in[3];
    const float* b0 = (const float*)d_in[4];
    const float* W1 = (const float*)d_in[5];
    const float* b1 = (const float*)d_in[6];
    const float* W2 = (const float*)d_in[7];
    const float* b2 = (const float*)d_in[8];
    float* out = (float*)d_out;

    const int N = N_NODES;
    const int E = in_sizes[1];
    const int NB = (N + SCAN_CHUNK - 1) / SCAN_CHUNK;
    const int GT = (N + 63) / 64;
    const int echunk = (E + GT - 1) / GT;

    // workspace layout (~48 MB)
    float* ns = (float*)d_ws;                       // N
    float* nd = ns + N;                             // N
    unsigned short* Hb = (unsigned short*)(nd + N); // N*64 bf16 (reused per layer)
    float* G = (float*)(Hb + (size_t)N * 64);       // N*64 fp32 (agg out, next gemm in)
    int* row_ptr = (int*)(G + (size_t)N * 64);      // N+1
    int* cursor = row_ptr + (N + 1);                // N
    int* csr_src = cursor + N;                      // E
    int* degS = csr_src + E;                        // N
    int* degD = degS + N;                           // N
    int* bsums = degD + N;                          // NB

    // 1) interleaved degrees + layer-0 GEMM (unscaled)
    hipMemsetAsync(degS, 0, (size_t)N * sizeof(int), stream);
    hipMemsetAsync(degD, 0, (size_t)N * sizeof(int), stream);
    k_deg_gemm0<<<2 * GT, 256, 0, stream>>>(src, dst, E, echunk, degS, degD,
                                            feats, W0, Hb, N);

    // 2) scan degD -> row_ptr (+ norms), single-pass scatter, deferred ns scale
    k_block_sums<<<NB, 256, 0, stream>>>(degD, N, bsums);
    k_scan_bsums<<<1, 64, 0, stream>>>(bsums, NB, row_ptr, N);
    k_scan_write<<<NB, 256, 0, stream>>>(degD, degS, N, bsums, row_ptr, cursor, ns, nd);
    k_scatter<<<(E + 255) / 256, 256, 0, stream>>>(src, dst, E, cursor, csr_src);
    k_scale_h<<<(N * 32 + 255) / 256, 256, 0, stream>>>((unsigned int*)Hb, ns, N);

    const int agg_blocks = (N + 3) / 4;

    // ---- layer 0 agg + relu + log_softmax -> G ----
    k_agg_post<64, true><<<agg_blocks, 256, 0, stream>>>(row_ptr, csr_src, Hb, nd, b0, G, N);

    // ---- layer 1 ----
    k_gemm_scale<64><<<GT, 256, 0, stream>>>(G, W1, ns, Hb, N);
    k_agg_post<64, true><<<agg_blocks, 256, 0, stream>>>(row_ptr, csr_src, Hb, nd, b1, G, N);

    // ---- layer 2 ----
    k_gemm_scale<40><<<GT, 256, 0, stream>>>(G, W2, ns, Hb, N);
    k_agg_post<40, false><<<agg_blocks, 256, 0, stream>>>(row_ptr, csr_src, Hb, nd, b2, out, N);
}

// Round 6
// 528.643 us; speedup vs baseline: 1.3760x; 1.1120x over previous
//
#include <hip/hip_runtime.h>
#include <math.h>

#define N_NODES 100000
#define NBUCK ((N_NODES + 255) / 256)   // 391 dst-buckets of 256 nodes
#define CAP 8192                        // slots per bucket (mean 4096, +64 sigma)
#define ACHUNK 8192                     // edges per pass-A block

struct alignas(16) f4 { float v[4]; };
struct alignas(8) us4 { unsigned short v[4]; };

__device__ inline unsigned short f2bf(float x) {
    union { float f; unsigned int u; } v;
    v.f = x;
    unsigned int r = v.u + 0x7FFF + ((v.u >> 16) & 1);
    return (unsigned short)(r >> 16);
}

__device__ inline float bf2f(unsigned short h) {
    union { unsigned int u; float f; } v;
    v.u = ((unsigned int)h) << 16;
    return v.f;
}

// ---------------- K1: interleaved [bucketed edge partition + degs atomics] + layer-0 GEMM ----------------
// Pass-A blocks (every S-th blockIdx): chunk of ACHUNK edges -> LDS dst-bucket histogram,
// bulk-reserve bucket ranges (few global atomics), write packed (src<<8|dlocal) into bucket
// regions (contiguous streams). Also fires degs[src] atomics (the unavoidable drain).
// Other blocks: 64x64 GEMM tile of Hb0 = bf16(feats @ W0), unscaled (ns applied in pass B).
__global__ __launch_bounds__(256, 4) void k_passA_gemm0(const int* __restrict__ src,
                                                        const int* __restrict__ dst,
                                                        int E, int nchunk, int S,
                                                        int* __restrict__ degs,
                                                        int* __restrict__ bcur,
                                                        int* __restrict__ packed,
                                                        const float* __restrict__ A,
                                                        const float* __restrict__ W,
                                                        unsigned short* __restrict__ C,
                                                        int n) {
    __shared__ __align__(16) float Ws[64 * 64];
    __shared__ __align__(16) float Asm[64 * 68];

    const int tid = threadIdx.x;
    const int b = blockIdx.x;

    if ((b % S == 0) && (b / S < nchunk)) {
        // ---- pass A: bucketed partition ----
        int* hist = (int*)Ws;          // NBUCK
        int* cur = hist + NBUCK;       // NBUCK
        const int base = (b / S) * ACHUNK;
        const int lim = min(E, base + ACHUNK);

        for (int i = tid; i < NBUCK; i += 256) hist[i] = 0;
        __syncthreads();
        for (int i = base + tid; i < lim; i += 256) {
            int s = src[i];
            int d = dst[i];
            atomicAdd(&degs[s], 1);          // global, fire-and-forget
            atomicAdd(&hist[d >> 8], 1);     // LDS
        }
        __syncthreads();
        for (int i = tid; i < NBUCK; i += 256) {
            int c = hist[i];
            cur[i] = (c > 0) ? atomicAdd(&bcur[i], c) : 0;  // bulk reservation
        }
        __syncthreads();
        for (int i = base + tid; i < lim; i += 256) {
            int s = src[i];
            int d = dst[i];
            int bk = d >> 8;
            int p = atomicAdd(&cur[bk], 1);  // LDS
            packed[(size_t)bk * CAP + p] = (s << 8) | (d & 255);
        }
        return;
    }

    // ---- GEMM tile ----
    const int nA = min((b + S - 1) / S, nchunk);  // pass-A ids below b
    const int r0 = (b - nA) * 64;
    const int tr = tid >> 4;
    const int tc = tid & 15;

    float acc[4][4];
#pragma unroll
    for (int i = 0; i < 4; ++i)
#pragma unroll
        for (int j = 0; j < 4; ++j) acc[i][j] = 0.0f;

    for (int kh = 0; kh < 2; ++kh) {
        for (int i = tid; i < 64 * 64; i += 256) {
            int k = i >> 6;
            int c = i & 63;
            Ws[i] = W[(kh * 64 + k) * 64 + c];
        }
        for (int i = tid * 4; i < 64 * 64; i += 1024) {
            int r = i >> 6;
            int c = i & 63;
            f4 v;
            if (r0 + r < n) {
                v = *(const f4*)&A[(size_t)(r0 + r) * 128 + kh * 64 + c];
            } else {
                v.v[0] = v.v[1] = v.v[2] = v.v[3] = 0.0f;
            }
            *(f4*)&Asm[r * 68 + c] = v;
        }
        __syncthreads();

        for (int k = 0; k < 64; k += 4) {
            f4 av[4], wv[4];
#pragma unroll
            for (int i = 0; i < 4; ++i)
                av[i] = *(const f4*)&Asm[(tr * 4 + i) * 68 + k];
#pragma unroll
            for (int kk = 0; kk < 4; ++kk)
                wv[kk] = *(const f4*)&Ws[(k + kk) * 64 + tc * 4];
#pragma unroll
            for (int i = 0; i < 4; ++i)
#pragma unroll
                for (int j = 0; j < 4; ++j)
                    acc[i][j] += av[i].v[0] * wv[0].v[j] + av[i].v[1] * wv[1].v[j] +
                                 av[i].v[2] * wv[2].v[j] + av[i].v[3] * wv[3].v[j];
        }
        __syncthreads();
    }

#pragma unroll
    for (int i = 0; i < 4; ++i) {
        int row = r0 + tr * 4 + i;
        if (row < n) {
            us4 o;
#pragma unroll
            for (int j = 0; j < 4; ++j) o.v[j] = f2bf(acc[i][j]);
            *(us4*)&C[(size_t)row * 64 + tc * 4] = o;
        }
    }
}

// ---------------- K2: per-bucket CSR build + norms + H ns-scale ----------------
// One block per bucket (256 nodes): LDS count -> LDS scan -> row_beg/row_end, nd, ns,
// LDS-cursor scatter of csr_src into the bucket's L2-resident window, H rows *= ns.
__global__ __launch_bounds__(256) void k_passB(const int* __restrict__ bcur,
                                               const int* __restrict__ packed,
                                               const int* __restrict__ degs,
                                               int* __restrict__ csr_src,
                                               int* __restrict__ row_beg,
                                               int* __restrict__ row_end,
                                               float* __restrict__ ns,
                                               float* __restrict__ nd,
                                               unsigned int* __restrict__ Hd,
                                               int n) {
    __shared__ int cnt[256];
    __shared__ int sc[256];
    __shared__ int cur[256];
    __shared__ float nsf[256];

    const int b = blockIdx.x;
    const int tid = threadIdx.x;
    const int n0 = b * 256;
    const int nn = min(256, n - n0);
    const int m = min(bcur[b], CAP);
    const int* pk = packed + (size_t)b * CAP;

    cnt[tid] = 0;
    __syncthreads();
    for (int i = tid; i < m; i += 256) atomicAdd(&cnt[pk[i] & 255], 1);
    __syncthreads();
    int c = cnt[tid];
    sc[tid] = c;
    __syncthreads();
    for (int off = 1; off < 256; off <<= 1) {
        int t = (tid >= off) ? sc[tid - off] : 0;
        __syncthreads();
        sc[tid] += t;
        __syncthreads();
    }
    int excl = sc[tid] - c;
    cur[tid] = excl;
    if (tid < nn) {
        int v = n0 + tid;
        int beg = b * CAP + excl;
        row_beg[v] = beg;
        row_end[v] = beg + c;
        nd[v] = (c > 0) ? rsqrtf((float)c) : 0.0f;
        int dg = degs[v];
        float s = (dg > 0) ? rsqrtf((float)dg) : 0.0f;
        ns[v] = s;
        nsf[tid] = s;
    } else {
        nsf[tid] = 0.0f;
    }
    __syncthreads();
    for (int i = tid; i < m; i += 256) {
        int w = pk[i];
        int v = w & 255;
        int p = atomicAdd(&cur[v], 1);  // LDS
        csr_src[(size_t)b * CAP + p] = w >> 8;
    }
    // scale H rows of this bucket's nodes by ns (deferred layer-0 scale)
    for (int i = tid; i < nn * 32; i += 256) {
        int r = i >> 5;
        float s = nsf[r];
        size_t gi = (size_t)(n0 + r) * 32 + (i & 31);
        unsigned int u = Hd[gi];
        float lo = bf2f((unsigned short)(u & 0xffffu)) * s;
        float hi = bf2f((unsigned short)(u >> 16)) * s;
        Hd[gi] = (unsigned int)f2bf(lo) | ((unsigned int)f2bf(hi) << 16);
    }
}

// ---------------- GEMM (K=64): C = bf16((A @ W) * ns[row]) ----------------
template <int OUT>
__global__ __launch_bounds__(256, 4) void k_gemm_scale(const float* __restrict__ A,
                                                       const float* __restrict__ W,
                                                       const float* __restrict__ ns,
                                                       unsigned short* __restrict__ C,
                                                       int n) {
    __shared__ __align__(16) float Ws[64 * 64];
    __shared__ __align__(16) float Asm[64 * 68];

    const int tid = threadIdx.x;
    const int r0 = blockIdx.x * 64;

    for (int i = tid; i < 64 * 64; i += 256) {
        int k = i >> 6;
        int c = i & 63;
        Ws[i] = (c < OUT) ? W[k * OUT + c] : 0.0f;
    }
    for (int i = tid * 4; i < 64 * 64; i += 1024) {
        int r = i >> 6;
        int c = i & 63;
        f4 v;
        if (r0 + r < n) {
            v = *(const f4*)&A[(size_t)(r0 + r) * 64 + c];
        } else {
            v.v[0] = v.v[1] = v.v[2] = v.v[3] = 0.0f;
        }
        *(f4*)&Asm[r * 68 + c] = v;
    }
    __syncthreads();

    const int tr = tid >> 4;
    const int tc = tid & 15;

    float acc[4][4];
#pragma unroll
    for (int i = 0; i < 4; ++i)
#pragma unroll
        for (int j = 0; j < 4; ++j) acc[i][j] = 0.0f;

    for (int k = 0; k < 64; k += 4) {
        f4 av[4], wv[4];
#pragma unroll
        for (int i = 0; i < 4; ++i)
            av[i] = *(const f4*)&Asm[(tr * 4 + i) * 68 + k];
#pragma unroll
        for (int kk = 0; kk < 4; ++kk)
            wv[kk] = *(const f4*)&Ws[(k + kk) * 64 + tc * 4];
#pragma unroll
        for (int i = 0; i < 4; ++i)
#pragma unroll
            for (int j = 0; j < 4; ++j)
                acc[i][j] += av[i].v[0] * wv[0].v[j] + av[i].v[1] * wv[1].v[j] +
                             av[i].v[2] * wv[2].v[j] + av[i].v[3] * wv[3].v[j];
    }

    if (tc * 4 < OUT) {
#pragma unroll
        for (int i = 0; i < 4; ++i) {
            int row = r0 + tr * 4 + i;
            if (row < n) {
                float s = ns[row];
                us4 o;
#pragma unroll
                for (int j = 0; j < 4; ++j) o.v[j] = f2bf(acc[i][j] * s);
                *(us4*)&C[(size_t)row * OUT + tc * 4] = o;
            }
        }
    }
}

// ---------------- fused CSR aggregate (bf16 gather) + (*nd + b) + relu? + log_softmax ----------------
template <int D, bool RELU>
__global__ __launch_bounds__(256) void k_agg_post(const int* __restrict__ row_beg,
                                                  const int* __restrict__ row_end,
                                                  const int* __restrict__ csr_src,
                                                  const unsigned short* __restrict__ H,
                                                  const float* __restrict__ nd,
                                                  const float* __restrict__ b,
                                                  float* __restrict__ Out,
                                                  int n) {
    int node = blockIdx.x * 4 + (threadIdx.x >> 6);
    int lane = threadIdx.x & 63;
    if (node >= n) return;

    int beg = row_beg[node];
    int end = row_end[node];
    bool active = lane < D;

    float a0 = 0.f, a1 = 0.f, a2 = 0.f, a3 = 0.f;
    for (int i = beg; i < end; i += 64) {
        int cnt = min(64, end - i);
        int idx = (lane < cnt) ? csr_src[i + lane] : 0;
        int j = 0;
        for (; j + 4 <= cnt; j += 4) {
            int s0 = __shfl(idx, j);
            int s1 = __shfl(idx, j + 1);
            int s2 = __shfl(idx, j + 2);
            int s3 = __shfl(idx, j + 3);
            if (active) {
                a0 += bf2f(H[(size_t)s0 * D + lane]);
                a1 += bf2f(H[(size_t)s1 * D + lane]);
                a2 += bf2f(H[(size_t)s2 * D + lane]);
                a3 += bf2f(H[(size_t)s3 * D + lane]);
            }
        }
        for (; j < cnt; ++j) {
            int s = __shfl(idx, j);
            if (active) a0 += bf2f(H[(size_t)s * D + lane]);
        }
    }
    float acc = (a0 + a1) + (a2 + a3);

    float x = -INFINITY;
    if (active) {
        x = acc * nd[node] + b[lane];
        if (RELU) x = fmaxf(x, 0.0f);
    }
    float m = x;
#pragma unroll
    for (int off = 32; off > 0; off >>= 1) m = fmaxf(m, __shfl_xor(m, off));
    float ex = active ? expf(x - m) : 0.0f;
    float ssum = ex;
#pragma unroll
    for (int off = 32; off > 0; off >>= 1) ssum += __shfl_xor(ssum, off);
    if (active) Out[(size_t)node * D + lane] = (x - m) - logf(ssum);
}

extern "C" void kernel_launch(void* const* d_in, const int* in_sizes, int n_in,
                              void* d_out, int out_size, void* d_ws, size_t ws_size,
                              hipStream_t stream) {
    const float* feats = (const float*)d_in[0];
    const int* src = (const int*)d_in[1];
    const int* dst = (const int*)d_in[2];
    const float* W0 = (const float*)d_in[3];
    const float* b0 = (const float*)d_in[4];
    const float* W1 = (const float*)d_in[5];
    const float* b1 = (const float*)d_in[6];
    const float* W2 = (const float*)d_in[7];
    const float* b2 = (const float*)d_in[8];
    float* out = (float*)d_out;

    const int N = N_NODES;
    const int E = in_sizes[1];
    const int GT = (N + 63) / 64;                       // 1563 gemm tiles
    const int NCHUNK = (E + ACHUNK - 1) / ACHUNK;       // 196 pass-A chunks
    const int grid1 = GT + NCHUNK;
    int S = grid1 / NCHUNK;                             // interleave stride
    if (S < 1) S = 1;

    // workspace layout (~66 MB)
    float* ns = (float*)d_ws;                           // N
    float* nd = ns + N;                                 // N
    unsigned short* Hb = (unsigned short*)(nd + N);     // N*64 bf16
    float* G = (float*)(Hb + (size_t)N * 64);           // N*64 fp32
    int* packed = (int*)(G + (size_t)N * 64);           // NBUCK*CAP
    int* csr_src = packed + (size_t)NBUCK * CAP;        // NBUCK*CAP
    int* row_beg = csr_src + (size_t)NBUCK * CAP;       // N
    int* row_end = row_beg + N;                         // N
    int* degs = row_end + N;                            // N
    int* bcur = degs + N;                               // NBUCK

    hipMemsetAsync(degs, 0, (size_t)N * sizeof(int), stream);
    hipMemsetAsync(bcur, 0, (size_t)NBUCK * sizeof(int), stream);

    // 1) interleaved bucketed-partition + degs atomics + layer-0 GEMM (unscaled)
    k_passA_gemm0<<<grid1, 256, 0, stream>>>(src, dst, E, NCHUNK, S, degs, bcur,
                                             packed, feats, W0, Hb, N);

    // 2) per-bucket CSR build + norms + H ns-scale
    k_passB<<<NBUCK, 256, 0, stream>>>(bcur, packed, degs, csr_src, row_beg, row_end,
                                       ns, nd, (unsigned int*)Hb, N);

    const int agg_blocks = (N + 3) / 4;

    // ---- layer 0 agg + relu + log_softmax -> G ----
    k_agg_post<64, true><<<agg_blocks, 256, 0, stream>>>(row_beg, row_end, csr_src, Hb, nd, b0, G, N);

    // ---- layer 1 ----
    k_gemm_scale<64><<<GT, 256, 0, stream>>>(G, W1, ns, Hb, N);
    k_agg_post<64, true><<<agg_blocks, 256, 0, stream>>>(row_beg, row_end, csr_src, Hb, nd, b1, G, N);

    // ---- layer 2 ----
    k_gemm_scale<40><<<GT, 256, 0, stream>>>(G, W2, ns, Hb, N);
    k_agg_post<40, false><<<agg_blocks, 256, 0, stream>>>(row_beg, row_end, csr_src, Hb, nd, b2, out, N);
}

// Round 7
// 440.788 us; speedup vs baseline: 1.6503x; 1.1993x over previous
//
#include <hip/hip_runtime.h>
#include <math.h>

#define N_NODES 100000
#define NBUCK ((N_NODES + 255) / 256)   // 391 dst-buckets of 256 nodes
#define CAP 8192                        // slots per bucket (mean 4096, +64 sigma)
#define ACHUNK 1024                     // edges per pass-A block (small: keeps CUs oversubscribed)

struct alignas(16) f4 { float v[4]; };
struct alignas(8) us4 { unsigned short v[4]; };

__device__ inline unsigned short f2bf(float x) {
    union { float f; unsigned int u; } v;
    v.f = x;
    unsigned int r = v.u + 0x7FFF + ((v.u >> 16) & 1);
    return (unsigned short)(r >> 16);
}

__device__ inline float bf2f(unsigned short h) {
    union { unsigned int u; float f; } v;
    v.u = ((unsigned int)h) << 16;
    return v.f;
}

// ---------------- K1: interleaved [bucketed edge partition + degs atomics] + layer-0 GEMM ----------------
// Even blocks (b%S==0): chunk of ACHUNK edges -> LDS dst-bucket histogram, bulk-reserve bucket
// ranges (few global atomics), write packed (src<<8|dlocal) into bucket regions. Also fires
// degs[src] atomics (the unavoidable drain). Odd blocks: 64x64 GEMM tile of
// Hb0 = bf16(feats @ W0), unscaled (ns applied in pass B). 1:1 interleave keeps both types
// co-resident so atomic/scatter latency hides under GEMM VALU work for the whole kernel.
__global__ __launch_bounds__(256, 4) void k_passA_gemm0(const int* __restrict__ src,
                                                        const int* __restrict__ dst,
                                                        int E, int nchunk, int S,
                                                        int* __restrict__ degs,
                                                        int* __restrict__ bcur,
                                                        int* __restrict__ packed,
                                                        const float* __restrict__ A,
                                                        const float* __restrict__ W,
                                                        unsigned short* __restrict__ C,
                                                        int n) {
    __shared__ __align__(16) float Ws[64 * 64];
    __shared__ __align__(16) float Asm[64 * 68];

    const int tid = threadIdx.x;
    const int b = blockIdx.x;

    if ((b % S == 0) && (b / S < nchunk)) {
        // ---- pass A: bucketed partition ----
        int* hist = (int*)Ws;          // NBUCK
        int* cur = hist + NBUCK;       // NBUCK
        const int base = (b / S) * ACHUNK;
        const int lim = min(E, base + ACHUNK);

        for (int i = tid; i < NBUCK; i += 256) hist[i] = 0;
        __syncthreads();
        for (int i = base + tid; i < lim; i += 256) {
            int s = src[i];
            int d = dst[i];
            atomicAdd(&degs[s], 1);          // global, fire-and-forget
            atomicAdd(&hist[d >> 8], 1);     // LDS
        }
        __syncthreads();
        for (int i = tid; i < NBUCK; i += 256) {
            int c = hist[i];
            cur[i] = (c > 0) ? atomicAdd(&bcur[i], c) : 0;  // bulk reservation
        }
        __syncthreads();
        for (int i = base + tid; i < lim; i += 256) {
            int s = src[i];
            int d = dst[i];
            int bk = d >> 8;
            int p = atomicAdd(&cur[bk], 1);  // LDS
            packed[(size_t)bk * CAP + p] = (s << 8) | (d & 255);
        }
        return;
    }

    // ---- GEMM tile ----
    const int nA = min((b + S - 1) / S, nchunk);  // pass-A ids below b
    const int r0 = (b - nA) * 64;
    const int tr = tid >> 4;
    const int tc = tid & 15;

    float acc[4][4];
#pragma unroll
    for (int i = 0; i < 4; ++i)
#pragma unroll
        for (int j = 0; j < 4; ++j) acc[i][j] = 0.0f;

    for (int kh = 0; kh < 2; ++kh) {
        for (int i = tid; i < 64 * 64; i += 256) {
            int k = i >> 6;
            int c = i & 63;
            Ws[i] = W[(kh * 64 + k) * 64 + c];
        }
        for (int i = tid * 4; i < 64 * 64; i += 1024) {
            int r = i >> 6;
            int c = i & 63;
            f4 v;
            if (r0 + r < n) {
                v = *(const f4*)&A[(size_t)(r0 + r) * 128 + kh * 64 + c];
            } else {
                v.v[0] = v.v[1] = v.v[2] = v.v[3] = 0.0f;
            }
            *(f4*)&Asm[r * 68 + c] = v;
        }
        __syncthreads();

        for (int k = 0; k < 64; k += 4) {
            f4 av[4], wv[4];
#pragma unroll
            for (int i = 0; i < 4; ++i)
                av[i] = *(const f4*)&Asm[(tr * 4 + i) * 68 + k];
#pragma unroll
            for (int kk = 0; kk < 4; ++kk)
                wv[kk] = *(const f4*)&Ws[(k + kk) * 64 + tc * 4];
#pragma unroll
            for (int i = 0; i < 4; ++i)
#pragma unroll
                for (int j = 0; j < 4; ++j)
                    acc[i][j] += av[i].v[0] * wv[0].v[j] + av[i].v[1] * wv[1].v[j] +
                                 av[i].v[2] * wv[2].v[j] + av[i].v[3] * wv[3].v[j];
        }
        __syncthreads();
    }

#pragma unroll
    for (int i = 0; i < 4; ++i) {
        int row = r0 + tr * 4 + i;
        if (row < n) {
            us4 o;
#pragma unroll
            for (int j = 0; j < 4; ++j) o.v[j] = f2bf(acc[i][j]);
            *(us4*)&C[(size_t)row * 64 + tc * 4] = o;
        }
    }
}

// ---------------- K2: per-bucket CSR build + norms + H ns-scale ----------------
__global__ __launch_bounds__(256) void k_passB(const int* __restrict__ bcur,
                                               const int* __restrict__ packed,
                                               const int* __restrict__ degs,
                                               int* __restrict__ csr_src,
                                               int* __restrict__ row_beg,
                                               int* __restrict__ row_end,
                                               float* __restrict__ ns,
                                               float* __restrict__ nd,
                                               unsigned int* __restrict__ Hd,
                                               int n) {
    __shared__ int cnt[256];
    __shared__ int sc[256];
    __shared__ int cur[256];
    __shared__ float nsf[256];

    const int b = blockIdx.x;
    const int tid = threadIdx.x;
    const int n0 = b * 256;
    const int nn = min(256, n - n0);
    const int m = min(bcur[b], CAP);
    const int* pk = packed + (size_t)b * CAP;

    cnt[tid] = 0;
    __syncthreads();
    for (int i = tid; i < m; i += 256) atomicAdd(&cnt[pk[i] & 255], 1);
    __syncthreads();
    int c = cnt[tid];
    sc[tid] = c;
    __syncthreads();
    for (int off = 1; off < 256; off <<= 1) {
        int t = (tid >= off) ? sc[tid - off] : 0;
        __syncthreads();
        sc[tid] += t;
        __syncthreads();
    }
    int excl = sc[tid] - c;
    cur[tid] = excl;
    if (tid < nn) {
        int v = n0 + tid;
        int beg = b * CAP + excl;
        row_beg[v] = beg;
        row_end[v] = beg + c;
        nd[v] = (c > 0) ? rsqrtf((float)c) : 0.0f;
        int dg = degs[v];
        float s = (dg > 0) ? rsqrtf((float)dg) : 0.0f;
        ns[v] = s;
        nsf[tid] = s;
    } else {
        nsf[tid] = 0.0f;
    }
    __syncthreads();
    for (int i = tid; i < m; i += 256) {
        int w = pk[i];
        int v = w & 255;
        int p = atomicAdd(&cur[v], 1);  // LDS
        csr_src[(size_t)b * CAP + p] = w >> 8;
    }
    // scale H rows of this bucket's nodes by ns (deferred layer-0 scale)
    for (int i = tid; i < nn * 32; i += 256) {
        int r = i >> 5;
        float s = nsf[r];
        size_t gi = (size_t)(n0 + r) * 32 + (i & 31);
        unsigned int u = Hd[gi];
        float lo = bf2f((unsigned short)(u & 0xffffu)) * s;
        float hi = bf2f((unsigned short)(u >> 16)) * s;
        Hd[gi] = (unsigned int)f2bf(lo) | ((unsigned int)f2bf(hi) << 16);
    }
}

// ---------------- GEMM (K=64): C = bf16((A @ W) * ns[row]) ----------------
template <int OUT>
__global__ __launch_bounds__(256, 4) void k_gemm_scale(const float* __restrict__ A,
                                                       const float* __restrict__ W,
                                                       const float* __restrict__ ns,
                                                       unsigned short* __restrict__ C,
                                                       int n) {
    __shared__ __align__(16) float Ws[64 * 64];
    __shared__ __align__(16) float Asm[64 * 68];

    const int tid = threadIdx.x;
    const int r0 = blockIdx.x * 64;

    for (int i = tid; i < 64 * 64; i += 256) {
        int k = i >> 6;
        int c = i & 63;
        Ws[i] = (c < OUT) ? W[k * OUT + c] : 0.0f;
    }
    for (int i = tid * 4; i < 64 * 64; i += 1024) {
        int r = i >> 6;
        int c = i & 63;
        f4 v;
        if (r0 + r < n) {
            v = *(const f4*)&A[(size_t)(r0 + r) * 64 + c];
        } else {
            v.v[0] = v.v[1] = v.v[2] = v.v[3] = 0.0f;
        }
        *(f4*)&Asm[r * 68 + c] = v;
    }
    __syncthreads();

    const int tr = tid >> 4;
    const int tc = tid & 15;

    float acc[4][4];
#pragma unroll
    for (int i = 0; i < 4; ++i)
#pragma unroll
        for (int j = 0; j < 4; ++j) acc[i][j] = 0.0f;

    for (int k = 0; k < 64; k += 4) {
        f4 av[4], wv[4];
#pragma unroll
        for (int i = 0; i < 4; ++i)
            av[i] = *(const f4*)&Asm[(tr * 4 + i) * 68 + k];
#pragma unroll
        for (int kk = 0; kk < 4; ++kk)
            wv[kk] = *(const f4*)&Ws[(k + kk) * 64 + tc * 4];
#pragma unroll
        for (int i = 0; i < 4; ++i)
#pragma unroll
            for (int j = 0; j < 4; ++j)
                acc[i][j] += av[i].v[0] * wv[0].v[j] + av[i].v[1] * wv[1].v[j] +
                             av[i].v[2] * wv[2].v[j] + av[i].v[3] * wv[3].v[j];
    }

    if (tc * 4 < OUT) {
#pragma unroll
        for (int i = 0; i < 4; ++i) {
            int row = r0 + tr * 4 + i;
            if (row < n) {
                float s = ns[row];
                us4 o;
#pragma unroll
                for (int j = 0; j < 4; ++j) o.v[j] = f2bf(acc[i][j] * s);
                *(us4*)&C[(size_t)row * OUT + tc * 4] = o;
            }
        }
    }
}

// ---------------- fused CSR aggregate (bf16 gather) + (*nd + b) + relu? + log_softmax ----------------
template <int D, bool RELU>
__global__ __launch_bounds__(256) void k_agg_post(const int* __restrict__ row_beg,
                                                  const int* __restrict__ row_end,
                                                  const int* __restrict__ csr_src,
                                                  const unsigned short* __restrict__ H,
                                                  const float* __restrict__ nd,
                                                  const float* __restrict__ b,
                                                  float* __restrict__ Out,
                                                  int n) {
    int node = blockIdx.x * 4 + (threadIdx.x >> 6);
    int lane = threadIdx.x & 63;
    if (node >= n) return;

    int beg = row_beg[node];
    int end = row_end[node];
    bool active = lane < D;

    float a0 = 0.f, a1 = 0.f, a2 = 0.f, a3 = 0.f;
    for (int i = beg; i < end; i += 64) {
        int cnt = min(64, end - i);
        int idx = (lane < cnt) ? csr_src[i + lane] : 0;
        int j = 0;
        for (; j + 4 <= cnt; j += 4) {
            int s0 = __shfl(idx, j);
            int s1 = __shfl(idx, j + 1);
            int s2 = __shfl(idx, j + 2);
            int s3 = __shfl(idx, j + 3);
            if (active) {
                a0 += bf2f(H[(size_t)s0 * D + lane]);
                a1 += bf2f(H[(size_t)s1 * D + lane]);
                a2 += bf2f(H[(size_t)s2 * D + lane]);
                a3 += bf2f(H[(size_t)s3 * D + lane]);
            }
        }
        for (; j < cnt; ++j) {
            int s = __shfl(idx, j);
            if (active) a0 += bf2f(H[(size_t)s * D + lane]);
        }
    }
    float acc = (a0 + a1) + (a2 + a3);

    float x = -INFINITY;
    if (active) {
        x = acc * nd[node] + b[lane];
        if (RELU) x = fmaxf(x, 0.0f);
    }
    float m = x;
#pragma unroll
    for (int off = 32; off > 0; off >>= 1) m = fmaxf(m, __shfl_xor(m, off));
    float ex = active ? expf(x - m) : 0.0f;
    float ssum = ex;
#pragma unroll
    for (int off = 32; off > 0; off >>= 1) ssum += __shfl_xor(ssum, off);
    if (active) Out[(size_t)node * D + lane] = (x - m) - logf(ssum);
}

extern "C" void kernel_launch(void* const* d_in, const int* in_sizes, int n_in,
                              void* d_out, int out_size, void* d_ws, size_t ws_size,
                              hipStream_t stream) {
    const float* feats = (const float*)d_in[0];
    const int* src = (const int*)d_in[1];
    const int* dst = (const int*)d_in[2];
    const float* W0 = (const float*)d_in[3];
    const float* b0 = (const float*)d_in[4];
    const float* W1 = (const float*)d_in[5];
    const float* b1 = (const float*)d_in[6];
    const float* W2 = (const float*)d_in[7];
    const float* b2 = (const float*)d_in[8];
    float* out = (float*)d_out;

    const int N = N_NODES;
    const int E = in_sizes[1];
    const int GT = (N + 63) / 64;                       // 1563 gemm tiles
    const int NCHUNK = (E + ACHUNK - 1) / ACHUNK;       // 1563 pass-A chunks
    const int grid1 = GT + NCHUNK;
    int S = grid1 / NCHUNK;                             // interleave stride (=2)
    if (S < 1) S = 1;

    // workspace layout (~66 MB)
    float* ns = (float*)d_ws;                           // N
    float* nd = ns + N;                                 // N
    unsigned short* Hb = (unsigned short*)(nd + N);     // N*64 bf16
    float* G = (float*)(Hb + (size_t)N * 64);           // N*64 fp32
    int* packed = (int*)(G + (size_t)N * 64);           // NBUCK*CAP
    int* csr_src = packed + (size_t)NBUCK * CAP;        // NBUCK*CAP
    int* row_beg = csr_src + (size_t)NBUCK * CAP;       // N
    int* row_end = row_beg + N;                         // N
    int* degs = row_end + N;                            // N
    int* bcur = degs + N;                               // NBUCK

    hipMemsetAsync(degs, 0, (size_t)N * sizeof(int), stream);
    hipMemsetAsync(bcur, 0, (size_t)NBUCK * sizeof(int), stream);

    // 1) interleaved bucketed-partition + degs atomics + layer-0 GEMM (unscaled)
    k_passA_gemm0<<<grid1, 256, 0, stream>>>(src, dst, E, NCHUNK, S, degs, bcur,
                                             packed, feats, W0, Hb, N);

    // 2) per-bucket CSR build + norms + H ns-scale
    k_passB<<<NBUCK, 256, 0, stream>>>(bcur, packed, degs, csr_src, row_beg, row_end,
                                       ns, nd, (unsigned int*)Hb, N);

    const int agg_blocks = (N + 3) / 4;

    // ---- layer 0 agg + relu + log_softmax -> G ----
    k_agg_post<64, true><<<agg_blocks, 256, 0, stream>>>(row_beg, row_end, csr_src, Hb, nd, b0, G, N);

    // ---- layer 1 ----
    k_gemm_scale<64><<<GT, 256, 0, stream>>>(G, W1, ns, Hb, N);
    k_agg_post<64, true><<<agg_blocks, 256, 0, stream>>>(row_beg, row_end, csr_src, Hb, nd, b1, G, N);

    // ---- layer 2 ----
    k_gemm_scale<40><<<GT, 256, 0, stream>>>(G, W2, ns, Hb, N);
    k_agg_post<40, false><<<agg_blocks, 256, 0, stream>>>(row_beg, row_end, csr_src, Hb, nd, b2, out, N);
}